// Round 5
// baseline (204.197 us; speedup 1.0000x reference)
//
#include <hip/hip_runtime.h>

#define KCODES 512
#define DIM    64
#define PXB    256     // pixels per block = one 16x16 image
#define NCT    32
#define MARGIN 0.125f

typedef __attribute__((ext_vector_type(8))) short        short8;
typedef __attribute__((ext_vector_type(8))) _Float16     half8;
typedef __attribute__((ext_vector_type(4))) float        floatx4;
typedef __attribute__((ext_vector_type(2))) unsigned int uint2v;

// k-slot permutation dictated by ds_read_b64_tr_b16's fixed 4x16 stride
__device__ __host__ inline int sigma_dim(int p) {
    return ((p >> 5) << 5) + (((p >> 2) & 1) << 4) + (((p >> 3) & 3) << 2) + (p & 3);
}

// setup: enorm (serial fmaf, bit-identical), e -> fp16(-2e) swizzled + sigma
__global__ __launch_bounds__(256) void vq_setup(const float* __restrict__ e,
        float* __restrict__ enorm, _Float16* __restrict__ ehf,
        float* __restrict__ counts, unsigned* __restrict__ tick)
{
    const int tg = blockIdx.x * 256 + threadIdx.x;
    const int c = tg >> 6, j = tg & 63;
    const int g = j >> 3, i = j & 7;
    const int gs = g ^ (c & 7);
    const int dsrc = sigma_dim(gs * 8 + i);
    ehf[tg] = (_Float16)(-2.f * e[c * DIM + dsrc]);
    if (tg < KCODES) {
        const float* er = e + tg * DIM;
        float s = 0.f;
        #pragma unroll
        for (int d = 0; d < DIM; ++d) s = fmaf(er[d], er[d], s);
        enorm[tg]  = s;
        counts[tg] = 0.f;
        if (tg == 0) *tick = 0u;
    }
}

__device__ inline unsigned mono(float f) {
    unsigned u = __float_as_uint(f);
    return (u & 0x80000000u) ? ~u : (u | 0x80000000u);
}
__device__ inline float unmono(unsigned u) {
    return __uint_as_float((u & 0x80000000u) ? (u & 0x7FFFFFFFu) : ~u);
}

#define DPP64(dst, src, CTRL) {                                                       \
    int _lo = __builtin_amdgcn_update_dpp(0, (int)(unsigned)((src) & 0xFFFFFFFFull),  \
                                          CTRL, 0xF, 0xF, true);                      \
    int _hi = __builtin_amdgcn_update_dpp(0, (int)(unsigned)((src) >> 32),            \
                                          CTRL, 0xF, 0xF, true);                      \
    dst = (((unsigned long long)(unsigned)_hi) << 32) | (unsigned)_lo; }

#define MERGE_STEP(CTRL) {                                                            \
    unsigned long long o1, o2; DPP64(o1, k1, CTRL); DPP64(o2, k2, CTRL);              \
    unsigned long long mx  = k1 > o1 ? k1 : o1;                                       \
    unsigned long long mn2 = k2 < o2 ? k2 : o2;                                       \
    k1 = k1 < o1 ? k1 : o1;                                                           \
    k2 = mx < mn2 ? mx : mn2; }

__global__ __launch_bounds__(512, 4) void vq_main(
        const float* __restrict__ z, const float* __restrict__ e,
        const _Float16* __restrict__ ehf, const float* __restrict__ enorm,
        const float* __restrict__ N, float* __restrict__ zq,
        float* __restrict__ counts, unsigned* __restrict__ tick,
        float* __restrict__ outN)
{
    __shared__ __align__(16) _Float16 S[KCODES * DIM];  // 64 KB: z-tile, then e-table
    __shared__ float ens[KCODES];
    __shared__ int   hist[KCODES];
    __shared__ int   idxs[PXB];
    __shared__ int   ref2[PXB];
    __shared__ int   lastflag;

    const int t    = threadIdx.x;
    const int b    = blockIdx.x;      // = image index
    const int lane = t & 63;
    const int wave = t >> 6;          // 0..7
    const int n16  = lane & 15;
    const int g4   = lane >> 4;

    ens[t] = enorm[t]; hist[t] = 0;   // 512 threads == KCODES

    // ---- phase 1: z loads (remapped for LDS bank spread) -------------------
    // (i, lane) -> dim d = (wave + (i&1)*8)*4 + g4, pixel-quad px4 = (i>>1)*16 + n16.
    // Same LDS image as before (addr = chunk*1024h + d*16 + px&15); only the
    // writing thread changed: write banks = g4*8 + (n16&3)*2 -> 4-way (was 8).
    const float* zimg = z + (size_t)b * (DIM * 256);
    float4 v[8];
    #pragma unroll
    for (int i = 0; i < 8; ++i) {
        const int d   = (wave + (i & 1) * 8) * 4 + g4;
        const int px4 = (i >> 1) * 16 + n16;
        v[i] = *(const float4*)(zimg + (size_t)d * 256 + px4 * 4);
    }
    // e-table prefetch to registers (latency hides under phases 1-2)
    short8 ev[8];
    {
        const short8* src = (const short8*)ehf;
        #pragma unroll
        for (int k = 0; k < 8; ++k) ev[k] = src[t + k * 512];
    }
    // z-tile ds_writes
    #pragma unroll
    for (int i = 0; i < 8; ++i) {
        const int d   = (wave + (i & 1) * 8) * 4 + g4;
        const int px4 = (i >> 1) * 16 + n16;
        union { _Float16 h[4]; uint2v u; } pk;
        pk.h[0] = (_Float16)v[i].x; pk.h[1] = (_Float16)v[i].y;
        pk.h[2] = (_Float16)v[i].z; pk.h[3] = (_Float16)v[i].w;
        *(uint2v*)(S + (px4 >> 2) * 1024 + d * 16 + (px4 & 3) * 4) = pk.u;
    }
    __syncthreads();

    // ---- phase 2: A-fragments via ds_read_b64_tr_b16 -----------------------
    half8 A[2][2];
    {
        uint2v r[2][2][2];
        const int trb = n16 * 2 + g4 * 128;
        #pragma unroll
        for (int pt = 0; pt < 2; ++pt) {
            const int base = (wave * 2 + pt) * 2048 + trb;
            #pragma unroll
            for (int ks = 0; ks < 2; ++ks) {
                const int a0 = base + ks * 1024;
                asm volatile("ds_read_b64_tr_b16 %0, %1" : "=v"(r[pt][ks][0]) : "v"(a0));
                asm volatile("ds_read_b64_tr_b16 %0, %1" : "=v"(r[pt][ks][1]) : "v"(a0 + 512));
            }
        }
        asm volatile("s_waitcnt lgkmcnt(0)" ::: "memory");
        __builtin_amdgcn_sched_barrier(0);
        #pragma unroll
        for (int pt = 0; pt < 2; ++pt)
            #pragma unroll
            for (int ks = 0; ks < 2; ++ks) {
                union { unsigned int u[4]; half8 h; } pk;
                pk.u[0] = r[pt][ks][0].x; pk.u[1] = r[pt][ks][0].y;
                pk.u[2] = r[pt][ks][1].x; pk.u[3] = r[pt][ks][1].y;
                A[pt][ks] = pk.h;
            }
    }
    __syncthreads();   // tr-reads complete -> safe to overwrite S

    // ---- phase 3: e-table stage from prefetched registers ------------------
    {
        short8* dst = (short8*)S;
        #pragma unroll
        for (int k = 0; k < 8; ++k)
            dst[t + k * 512] = ev[k];
    }
    __syncthreads();

    // ---- phase 4: score loop ----------------------------------------------
    const int xr = n16 & 7;
    const int byte0 = n16 * 128 + (((g4    ) ^ xr) << 4);
    const int byte1 = n16 * 128 + (((4 | g4) ^ xr) << 4);
    const char* hb = (const char*)S;

    float bestv[2][4];
    int   bct[2][4];
    #pragma unroll
    for (int pt = 0; pt < 2; ++pt)
        #pragma unroll
        for (int r = 0; r < 4; ++r) { bestv[pt][r] = 3.4e38f; bct[pt][r] = 0; }

    #pragma unroll 2
    for (int ct = 0; ct < NCT; ++ct) {
        const int cb = ct * 2048;
        half8 B0 = *(const half8*)(hb + cb + byte0);
        half8 B1 = *(const half8*)(hb + cb + byte1);
        const float en = ens[ct * 16 + n16];
        #pragma unroll
        for (int pt = 0; pt < 2; ++pt) {
            floatx4 C = {en, en, en, en};
            C = __builtin_amdgcn_mfma_f32_16x16x32_f16(A[pt][0], B0, C, 0, 0, 0);
            C = __builtin_amdgcn_mfma_f32_16x16x32_f16(A[pt][1], B1, C, 0, 0, 0);
            #pragma unroll
            for (int r = 0; r < 4; ++r) {   // ascending ct: strict < = first-min
                float s = C[r];
                if (s < bestv[pt][r]) { bestv[pt][r] = s; bct[pt][r] = ct; }
            }
        }
    }

    // ---- phase 5: DPP top-2 argmin (no LDS ops) ----------------------------
    #pragma unroll
    for (int pt = 0; pt < 2; ++pt)
        #pragma unroll
        for (int r = 0; r < 4; ++r) {
            unsigned long long k1 =
                (((unsigned long long)mono(bestv[pt][r])) << 32)
                | (unsigned)(bct[pt][r] * 16 + n16);
            unsigned long long k2 = ~0ull;
            MERGE_STEP(0xB1);   // quad_perm [1,0,3,2]
            MERGE_STEP(0x4E);   // quad_perm [2,3,0,1]
            MERGE_STEP(0x124);  // row_ror:4
            MERGE_STEP(0x128);  // row_ror:8
            if (n16 == 0) {
                const int px = wave * 32 + pt * 16 + g4 * 4 + r;
                const float f1 = unmono((unsigned)(k1 >> 32));
                const float f2 = unmono((unsigned)(k2 >> 32));
                idxs[px] = (int)(k1 & 0xFFFFFFFFull);
                ref2[px] = (f2 - f1 < MARGIN) ? (int)(k2 & 0xFFFFFFFFull) : -1;
            }
        }

    __syncthreads();

    // ---- phase 6a: exact refine, then histogram final ids ------------------
    if (t < PXB) {
        int bi = idxs[t];
        const int r2 = ref2[t];
        if (r2 >= 0) {
            const float* zb = zimg + t;
            const float* e1 = e + bi * DIM;
            const float* e2 = e + r2 * DIM;
            float d1 = 0.f, d2 = 0.f;
            #pragma unroll
            for (int d = 0; d < DIM; ++d) {
                const float zd = zb[(size_t)d * 256];
                d1 = fmaf(zd, e1[d], d1);
                d2 = fmaf(zd, e2[d], d2);
            }
            const float s1 = fmaf(-2.f, d1, ens[bi]);
            const float s2 = fmaf(-2.f, d2, ens[r2]);
            if (s2 < s1 || (s2 == s1 && r2 < bi)) bi = r2;
            idxs[t] = bi;
        }
        atomicAdd(&hist[bi], 1);
    }
    __syncthreads();

    // ---- phase 6b: counts + ticket before the big gather -------------------
    { int h = hist[t]; if (h) atomicAdd(&counts[t], (float)h); }
    __syncthreads();
    if (t == 0) {
        __threadfence();
        unsigned o = __hip_atomic_fetch_add(tick, 1u, __ATOMIC_ACQ_REL,
                                            __HIP_MEMORY_SCOPE_AGENT);
        lastflag = (o == gridDim.x - 1u);
    }
    __syncthreads();

    // ---- phase 6c: gather stores ------------------------------------------
    {
        const int px = t & 255, dh = (t >> 8) * 32;
        const int bi = idxs[px];
        const float4* er4 = (const float4*)(e + bi * DIM + dh);
        float* ob = zq + (size_t)b * (DIM * 256) + (size_t)dh * 256 + px;
        #pragma unroll
        for (int q = 0; q < 8; ++q) {
            float4 w = er4[q];
            ob[(size_t)(4 * q + 0) * 256] = w.x;
            ob[(size_t)(4 * q + 1) * 256] = w.y;
            ob[(size_t)(4 * q + 2) * 256] = w.z;
            ob[(size_t)(4 * q + 3) * 256] = w.w;
        }
    }

    if (lastflag) {
        float c = __hip_atomic_load(&counts[t], __ATOMIC_RELAXED,
                                    __HIP_MEMORY_SCOPE_AGENT);
        outN[t] = 0.995f * N[t] + 0.005f * c;
    }
}

extern "C" void kernel_launch(void* const* d_in, const int* in_sizes, int n_in,
                              void* d_out, int out_size, void* d_ws, size_t ws_size,
                              hipStream_t stream) {
    const float* z = (const float*)d_in[0];
    const float* e = (const float*)d_in[1];
    const float* N = (const float*)d_in[2];
    float* out = (float*)d_out;
    const int nz     = in_sizes[0];            // 16777216
    const int npix   = nz / DIM;               // 262144
    const int blocks = npix / PXB;             // 1024

    char* ws = (char*)d_ws;
    float*     enorm  = (float*)(ws);
    float*     counts = (float*)(ws + 2048);
    unsigned*  tick   = (unsigned*)(ws + 4096);
    _Float16*  ehf    = (_Float16*)(ws + 4352);   // 64 KB swizzled+sigma

    vq_setup<<<(KCODES * DIM) / 256, 256, 0, stream>>>(e, enorm, ehf, counts, tick);
    vq_main<<<blocks, 512, 0, stream>>>(z, e, ehf, enorm, N, out, counts,
                                        tick, out + nz);
}